// Round 12
// baseline (280.149 us; speedup 1.0000x reference)
//
#include <hip/hip_runtime.h>
#include <math.h>

#define BB 8
#define CCH 256
#define LLEN 4096
#define L1V 4094
#define L2V 4092
#define L3V 4088
#define NCOL (BB * L2V)   // 32736

// ---------- prep: transpose all per-oc weight tables to [r][oc] (coalesced reads) ----------
__global__ void prep_kernel(const float* __restrict__ wa1, const float* __restrict__ wa2,
                            const float* __restrict__ w1, const float* __restrict__ w2,
                            const float* __restrict__ w3,
                            float* __restrict__ wt1T, float* __restrict__ wt2T,
                            float* __restrict__ w1T, float* __restrict__ w2T,
                            float* __restrict__ w3T) {
    int r = blockIdx.x;
    int o = threadIdx.x;
    if (r < 64) {
        wt1T[r * 256 + o] = wa1[o * 64 + r];
    } else if (r < 96) {
        wt2T[(r - 64) * 256 + o] = wa2[o * 32 + (r - 64)];
    } else if (r < 192) {
        w1T[(r - 96) * 256 + o] = w1[o * 96 + (r - 96)];
    } else if (r < 288) {
        w2T[(r - 192) * 256 + o] = w2[o * 96 + (r - 192)];
    } else {
        w3T[(r - 288) * 256 + o] = w3[o * 160 + (r - 288)];
    }
}

// ---------- K1+K2 fused: x [B,C,L] -> (conv1,shuffle) LDS -> (conv2,shuffle) t2 ----------
// History: (256,4) w/o sched_barriers spilled (34 batched ds_read dests = 136
// VGPR demand, rounds 7/8: 0.5GB fetch). (256,3) + sched_barriers: no spill but
// allocator spends the 170 headroom (144 used) -> 8 waves/CU (round 10).
// Now: (256,4) cap 128 + sched_barrier(0) every 8 p-iters bounding true peak
// demand to ~95-110 -> fits under 128 -> 16 waves/CU, no spill.
// Round 11 ran this on a throttled chip (control kernel attn +35%) -> resubmit
// for a clean A/B. Tripwire: FETCH >> 100MB means spill -> revert to (256,3).
__global__ __launch_bounds__(256, 4) void conv12_kernel(const float* __restrict__ x,
                                                        const float* __restrict__ w1T,
                                                        const float* __restrict__ b1,
                                                        const float* __restrict__ w2T,
                                                        const float* __restrict__ b2,
                                                        float* __restrict__ t2) {
    __shared__ float sm[9792];
    const int b = blockIdx.y;
    const int l0 = blockIdx.x * 32;
    const int t = threadIdx.x;

    // stage x: 256 rows x 36 floats (9 float4 per row), clamp tail reads
#pragma unroll
    for (int j = 0; j < 9; ++j) {
        int f = t + 256 * j;           // 0..2303
        int row = f / 9;
        int q = f - row * 9;
        size_t rb = (size_t)(b * CCH + row) * LLEN;
        float4 v;
        int base = l0 + 4 * q;
        if (base + 3 < LLEN) {
            v = *(const float4*)(x + rb + base);
        } else {
            v.x = x[rb + min(base + 0, LLEN - 1)];
            v.y = x[rb + min(base + 1, LLEN - 1)];
            v.z = x[rb + min(base + 2, LLEN - 1)];
            v.w = x[rb + min(base + 3, LLEN - 1)];
        }
        int a = row * 36 + (row >> 5) * 4 + 4 * q;
        *(float4*)&sm[a] = v;
    }
    __syncthreads();

    const int oc = t;
    const int go = t >> 5;

    // ---- conv1: 34 outputs per thread, two 17-output passes ----
    float acc[34];
#pragma unroll
    for (int l = 0; l < 34; ++l) acc[l] = 0.f;

#pragma unroll
    for (int pass = 0; pass < 2; ++pass) {
        const int ob = pass * 17;      // output base: 0 or 17
        const int qlo = pass * 4;      // q window: 0..4 or 4..8
        for (int i = 0; i < 32; ++i) {
            int base = (go * 32 + i) * 36 + go * 4;
            float wv0 = w1T[(i * 3 + 0) * 256 + oc];
            float wv1 = w1T[(i * 3 + 1) * 256 + oc];
            float wv2 = w1T[(i * 3 + 2) * 256 + oc];
#pragma unroll
            for (int qq = 0; qq < 5; ++qq) {
                int q = qlo + qq;
                float4 v = *(const float4*)&sm[base + 4 * q];
#pragma unroll
                for (int j = 0; j < 4; ++j) {
                    int e = 4 * q + j;           // compile-time after unroll
                    float xv = (&v.x)[j];
                    int d0 = e - ob;
                    if (d0 >= 0 && d0 < 17) acc[ob + d0] += wv0 * xv;
                    if (d0 - 1 >= 0 && d0 - 1 < 17) acc[ob + d0 - 1] += wv1 * xv;
                    if (d0 - 2 >= 0 && d0 - 2 < 17) acc[ob + d0 - 2] += wv2 * xv;
                }
            }
        }
    }
    float bias1 = b1[oc];
    // shuffled channel this thread produced, in conv2's skewed LDS layout
    int c1 = (oc & 31) * 8 + (oc >> 5);
    int col1 = (c1 >> 5) * 36 + (c1 & 31);

    __syncthreads();                    // all conv1 reads of xs complete
#pragma unroll
    for (int p = 0; p < 34; ++p) sm[p * 288 + col1] = acc[p] + bias1;
    __syncthreads();                    // t1 tile ready

    // ---- conv2: 32 outputs per thread (identical math to standalone conv2) ----
    float acc2[32];
#pragma unroll
    for (int l = 0; l < 32; ++l) acc2[l] = 0.f;

    for (int i4 = 0; i4 < 8; ++i4) {
        float wv[12];
#pragma unroll
        for (int z = 0; z < 12; ++z) wv[z] = w2T[(i4 * 12 + z) * 256 + oc];
        int colbase = go * 36 + i4 * 4;
#pragma unroll
        for (int p = 0; p < 34; ++p) {
            float4 rv = *(const float4*)&sm[p * 288 + colbase];
#pragma unroll
            for (int cc = 0; cc < 4; ++cc) {
                float xv = (&rv.x)[cc];
#pragma unroll
                for (int k = 0; k < 3; ++k) {
                    int l = p - k;
                    if (l >= 0 && l < 32) acc2[l] += wv[cc * 3 + k] * xv;
                }
            }
            // cap in-flight ds_read batching (VGPR pressure), keep indices static
            if ((p & 7) == 7) __builtin_amdgcn_sched_barrier(0);
        }
    }
    float bias2 = b2[oc];
    int nc = (oc & 31) * 8 + (oc >> 5);
    float* dst = t2 + (size_t)(b * L2V + l0) * CCH + nc;
#pragma unroll
    for (int l = 0; l < 32; ++l) {
        if (l0 + l < L2V) dst[(size_t)l * CCH] = acc2[l] + bias2;
    }
}

// ---------- K3: per-column sort + attention gate, in-place on t2 ----------
__device__ __forceinline__ void ce_pair(float& a, float& b, bool up) {
    float lo = fminf(a, b), hi = fmaxf(a, b);
    a = up ? lo : hi;
    b = up ? hi : lo;
}

// xor-shuffle within 32-lane halves via ds_swizzle immediate (no addr-calc VALU)
template<int LM>
__device__ __forceinline__ float swz(float x) {
    return __int_as_float(__builtin_amdgcn_ds_swizzle(__float_as_int(x), (LM << 10) | 0x1F));
}

// One merge step for ALL 4 columns at once: 16 independent shuffle->minmax chains
// per stage -> DS latency hidden by ILP.
template<int K, int J>
__device__ __forceinline__ void mstep(float v[4][4], int lane) {
    if constexpr (J >= 4) {
        constexpr int LM = J >> 2;
        const bool upper = (lane & LM) != 0;
#pragma unroll
        for (int r = 0; r < 4; ++r) {
            const bool dirUp = (((4 * lane + r) & K) == 0);   // indep of column
            const bool keepMin = (dirUp != upper);
#pragma unroll
            for (int c = 0; c < 4; ++c) {
                float other;
                if constexpr (LM == 32) other = __shfl_xor(v[c][r], 32, 64);
                else other = swz<LM>(v[c][r]);
                float lo = fminf(v[c][r], other), hi = fmaxf(v[c][r], other);
                v[c][r] = keepMin ? lo : hi;
            }
        }
    } else if constexpr (J == 2) {
#pragma unroll
        for (int r = 0; r < 2; ++r) {
            const bool up = (((4 * lane + r) & K) == 0);
#pragma unroll
            for (int c = 0; c < 4; ++c) ce_pair(v[c][r], v[c][r + 2], up);
        }
    } else {
#pragma unroll
        for (int r = 0; r < 4; r += 2) {
            const bool up = (((4 * lane + r) & K) == 0);
#pragma unroll
            for (int c = 0; c < 4; ++c) ce_pair(v[c][r], v[c][r + 1], up);
        }
    }
    if constexpr (J > 1) mstep<K, (J >> 1)>(v, lane);
}

template<int K>
__device__ __forceinline__ void msort(float v[4][4], int lane) {
    mstep<K, (K >> 1)>(v, lane);
    if constexpr (K < 256) msort<(K << 1)>(v, lane);
}

// One wave handles 4 columns. No inter-wave coupling: no __syncthreads.
__global__ __launch_bounds__(256, 5) void attn_kernel(float* __restrict__ t2,
                                                      const float* __restrict__ wt1T,
                                                      const float* __restrict__ wt2T,
                                                      const float* __restrict__ ba1,
                                                      const float* __restrict__ ba2) {
    __shared__ float sm[8192];           // 4 waves * 2048 floats = 32768 B
    const int t = threadIdx.x;
    const int wv = t >> 6;
    const int lane = t & 63;
    const int wbase = wv << 11;
    const int go = lane >> 3;            // group of outputs o = 4*lane+r

    float4 ba1v = *(const float4*)&ba1[4 * lane];
    float4 ba2v = *(const float4*)&ba2[4 * lane];

    const int colBase = blockIdx.x * 16 + wv * 4;   // grid sized exactly: always valid

    float4 hv[4];
#pragma unroll
    for (int cc = 0; cc < 4; ++cc) {
        hv[cc] = *(const float4*)(t2 + (size_t)(colBase + cc) * CCH + 4 * lane);
    }
    // h -> cat chunks 4..7 (xor-swizzled)
#pragma unroll
    for (int r = 0; r < 4; ++r) {
        int e = 4 * lane + r;
        int ch = (e >> 6) + 4;
        int slot = ch * 64 + ((e & 63) ^ ch);
        float4 vvv = make_float4((&hv[0].x)[r], (&hv[1].x)[r], (&hv[2].x)[r], (&hv[3].x)[r]);
        *(float4*)&sm[wbase + slot * 4] = vvv;
    }
    // sort all 4 columns simultaneously (interleaved stages)
    float v[4][4];
#pragma unroll
    for (int cc = 0; cc < 4; ++cc)
#pragma unroll
        for (int r = 0; r < 4; ++r) v[cc][r] = (&hv[cc].x)[r];
    msort<2>(v, lane);

    // sorted -> cat chunks 0..3 (xor-swizzled)
#pragma unroll
    for (int r = 0; r < 4; ++r) {
        int e = 4 * lane + r;
        int ch = e >> 6;
        int slot = ch * 64 + ((e & 63) ^ ch);
        float4 vvv = make_float4(v[0][r], v[1][r], v[2][r], v[3][r]);
        *(float4*)&sm[wbase + slot * 4] = vvv;
    }

    // a1[o] = ba1[o] + sum_i wa1[o][i] * cat[go*64+i]
    float4 acc[4];
#pragma unroll
    for (int cc = 0; cc < 4; ++cc) acc[cc] = make_float4(0.f, 0.f, 0.f, 0.f);
#pragma unroll 4
    for (int i = 0; i < 64; ++i) {
        float4 w4 = *(const float4*)&wt1T[i * 256 + 4 * lane];
        float4 cv = *(const float4*)&sm[wbase + (go * 64 + (i ^ go)) * 4];
#pragma unroll
        for (int cc = 0; cc < 4; ++cc) {
            float cvv = (&cv.x)[cc];
            acc[cc].x += w4.x * cvv;
            acc[cc].y += w4.y * cvv;
            acc[cc].z += w4.z * cvv;
            acc[cc].w += w4.w * cvv;
        }
    }
    // + bias, store a1 into reused buffer (padded: slotA = 5*lane + r, max 318 < 512)
#pragma unroll
    for (int r = 0; r < 4; ++r) {
        float bb = (&ba1v.x)[r];
        float4 vvv = make_float4((&acc[0].x)[r] + bb, (&acc[1].x)[r] + bb,
                                 (&acc[2].x)[r] + bb, (&acc[3].x)[r] + bb);
        *(float4*)&sm[wbase + (5 * lane + r) * 4] = vvv;
    }

    // a2[c] = sigmoid(ba2[c] + sum_i wa2[c][i] * a1[(j%8)*32 + j/8]), j = gc*32+i
    float4 acc2[4];
#pragma unroll
    for (int cc = 0; cc < 4; ++cc) acc2[cc] = make_float4(0.f, 0.f, 0.f, 0.f);
#pragma unroll 4
    for (int i = 0; i < 32; ++i) {
        float4 w4 = *(const float4*)&wt2T[i * 256 + 4 * lane];
        int idx = ((i & 7) << 5) + (go << 2) + (i >> 3);
        int slotA = idx + (idx >> 2);
        float4 av = *(const float4*)&sm[wbase + slotA * 4];
#pragma unroll
        for (int cc = 0; cc < 4; ++cc) {
            float avv = (&av.x)[cc];
            acc2[cc].x += w4.x * avv;
            acc2[cc].y += w4.y * avv;
            acc2[cc].z += w4.z * avv;
            acc2[cc].w += w4.w * avv;
        }
    }
    // gate + in-place store
#pragma unroll
    for (int cc = 0; cc < 4; ++cc) {
        float zx = acc2[cc].x + ba2v.x;
        float zy = acc2[cc].y + ba2v.y;
        float zz = acc2[cc].z + ba2v.z;
        float zw = acc2[cc].w + ba2v.w;
        float4 res;
        res.x = hv[cc].x * (1.f / (1.f + __expf(-zx)));
        res.y = hv[cc].y * (1.f / (1.f + __expf(-zy)));
        res.z = hv[cc].z * (1.f / (1.f + __expf(-zz)));
        res.w = hv[cc].w * (1.f / (1.f + __expf(-zw)));
        *(float4*)(t2 + (size_t)(colBase + cc) * CCH + 4 * lane) = res;
    }
}

// ---------- K4: grouped conv k=5 over t2 [B,L2,C] -> out [B,C,L3] ----------
// LDS [36][256] = 36 KB: compute reads are 2x broadcast (free), staging writes
// 1KB-contiguous per wave -> conflict-equivalent to skewed layout, 4 blocks/CU.
__global__ __launch_bounds__(256, 4) void conv3_kernel(const float* __restrict__ hm,
                                                       const float* __restrict__ w3T,
                                                       const float* __restrict__ b3,
                                                       float* __restrict__ out) {
    __shared__ float ts[9216];  // [36][256]
    const int b = blockIdx.y;
    const int l0 = blockIdx.x * 32;
    const int t = threadIdx.x;

#pragma unroll
    for (int j = 0; j < 9; ++j) {
        int f = t + 256 * j;            // exactly 2304 = 36*64
        int p = f >> 6;
        int c4 = (f & 63) * 4;
        int row = min(l0 + p, L2V - 1);
        float4 v = *(const float4*)(hm + (size_t)(b * L2V + row) * CCH + c4);
        *(float4*)&ts[p * 256 + c4] = v;
    }
    __syncthreads();

    const int oc = t;
    const int go = t >> 5;
    float acc[32];
#pragma unroll
    for (int l = 0; l < 32; ++l) acc[l] = 0.f;

    for (int i4 = 0; i4 < 8; ++i4) {
        float wv[20];
#pragma unroll
        for (int z = 0; z < 20; ++z) wv[z] = w3T[(i4 * 20 + z) * 256 + oc];
        int colbase = go * 32 + i4 * 4;
#pragma unroll
        for (int p = 0; p < 36; ++p) {
            float4 rv = *(const float4*)&ts[p * 256 + colbase];
#pragma unroll
            for (int cc = 0; cc < 4; ++cc) {
                float xv = (&rv.x)[cc];
#pragma unroll
                for (int k = 0; k < 5; ++k) {
                    int l = p - k;
                    if (l >= 0 && l < 32) acc[l] += wv[cc * 5 + k] * xv;
                }
            }
        }
    }
    float bias = b3[oc];
    float* dst = out + (size_t)(b * CCH + oc) * L3V + l0;
#pragma unroll
    for (int l4 = 0; l4 < 8; ++l4) {
        int gl = l0 + 4 * l4;
        if (gl + 3 < L3V) {
            float4 v;
            v.x = acc[4 * l4 + 0] + bias;
            v.y = acc[4 * l4 + 1] + bias;
            v.z = acc[4 * l4 + 2] + bias;
            v.w = acc[4 * l4 + 3] + bias;
            *(float4*)(dst + 4 * l4) = v;
        } else {
#pragma unroll
            for (int c = 0; c < 4; ++c) {
                if (gl + c < L3V) dst[4 * l4 + c] = acc[4 * l4 + c] + bias;
            }
        }
    }
}

extern "C" void kernel_launch(void* const* d_in, const int* in_sizes, int n_in,
                              void* d_out, int out_size, void* d_ws, size_t ws_size,
                              hipStream_t stream) {
    const float* x   = (const float*)d_in[0];
    const float* w1  = (const float*)d_in[1];
    const float* b1  = (const float*)d_in[2];
    const float* w2  = (const float*)d_in[3];
    const float* b2  = (const float*)d_in[4];
    const float* wa1 = (const float*)d_in[5];
    const float* ba1 = (const float*)d_in[6];
    const float* wa2 = (const float*)d_in[7];
    const float* ba2 = (const float*)d_in[8];
    const float* w3  = (const float*)d_in[9];
    const float* b3  = (const float*)d_in[10];
    float* out = (float*)d_out;

    char* ws = (char*)d_ws;
    float* t2   = (float*)(ws + ((size_t)32 << 20));            // 8*4092*256 f32 = 33.5 MB
    float* wt1T = (float*)(ws + ((size_t)64 << 20));            // 64*256 f32
    float* wt2T = wt1T + 64 * 256;                              // 32*256 f32
    float* w1T  = wt2T + 32 * 256;                              // 96*256 f32
    float* w2T  = w1T + 96 * 256;                               // 96*256 f32
    float* w3T  = w2T + 96 * 256;                               // 160*256 f32

    hipLaunchKernelGGL(prep_kernel, dim3(448), dim3(256), 0, stream,
                       wa1, wa2, w1, w2, w3, wt1T, wt2T, w1T, w2T, w3T);
    hipLaunchKernelGGL(conv12_kernel, dim3(128, BB), dim3(256), 0, stream,
                       x, w1T, b1, w2T, b2, t2);
    hipLaunchKernelGGL(attn_kernel, dim3(2046), dim3(256), 0, stream, t2, wt1T, wt2T, ba1, ba2);
    hipLaunchKernelGGL(conv3_kernel, dim3(128, BB), dim3(256), 0, stream, t2, w3T, b3, out);
}

// Round 14
// 261.748 us; speedup vs baseline: 1.0703x; 1.0703x over previous
//
#include <hip/hip_runtime.h>
#include <math.h>

#define BB 8
#define CCH 256
#define LLEN 4096
#define L1V 4094
#define L2V 4092
#define L3V 4088
#define NCOL (BB * L2V)   // 32736

// ---------- prep: transpose all per-oc weight tables to [r][oc] (coalesced reads) ----------
__global__ void prep_kernel(const float* __restrict__ wa1, const float* __restrict__ wa2,
                            const float* __restrict__ w1, const float* __restrict__ w2,
                            const float* __restrict__ w3,
                            float* __restrict__ wt1T, float* __restrict__ wt2T,
                            float* __restrict__ w1T, float* __restrict__ w2T,
                            float* __restrict__ w3T) {
    int r = blockIdx.x;
    int o = threadIdx.x;
    if (r < 64) {
        wt1T[r * 256 + o] = wa1[o * 64 + r];
    } else if (r < 96) {
        wt2T[(r - 64) * 256 + o] = wa2[o * 32 + (r - 64)];
    } else if (r < 192) {
        w1T[(r - 96) * 256 + o] = w1[o * 96 + (r - 96)];
    } else if (r < 288) {
        w2T[(r - 192) * 256 + o] = w2[o * 96 + (r - 192)];
    } else {
        w3T[(r - 288) * 256 + o] = w3[o * 160 + (r - 288)];
    }
}

// ---------- K1+K2 fused: x [B,C,L] -> (conv1,shuffle) LDS -> (conv2,shuffle) t2 ----------
// Round 13 (resubmit; container-level infra failure, kernel audited clean):
// 24-position tile for 5 blocks/CU (was 32-pos, 39.4KB LDS + 128 VGPR
// -> 4 blocks, ~10 waves/CU, VALUBusy 53%). Budget: x-tile 256x28+skew = 28.8KB,
// conv2 overlay [26][288] = 29.9KB -> LDS 30KB <= 32KB; VGPR peak ~75 (acc[26],
// acc2[24], window-4 sched_barriers bound in-flight reads to 16 regs) <= 102
// -> (256,5) = 20 waves/CU. Streaming order per output unchanged -> bit-identical.
// Tripwires: VGPR > 102 real or GB-scale FETCH/WRITE = spill -> revert to r12.
__global__ __launch_bounds__(256, 5) void conv12_kernel(const float* __restrict__ x,
                                                        const float* __restrict__ w1T,
                                                        const float* __restrict__ b1,
                                                        const float* __restrict__ w2T,
                                                        const float* __restrict__ b2,
                                                        float* __restrict__ t2) {
    __shared__ float sm[7488];          // max(x-tile 7196, [26][288]=7488) floats
    const int b = blockIdx.y;
    const int l0 = blockIdx.x * 24;
    const int t = threadIdx.x;

    // stage x: 256 rows x 28 floats (7 float4 per row), clamp tail reads
#pragma unroll
    for (int j = 0; j < 7; ++j) {
        int f = t + 256 * j;           // 0..1791 = 256*7
        int row = f / 7;
        int q = f - row * 7;
        size_t rb = (size_t)(b * CCH + row) * LLEN;
        float4 v;
        int base = l0 + 4 * q;
        if (base + 3 < LLEN) {
            v = *(const float4*)(x + rb + base);
        } else {
            v.x = x[rb + min(base + 0, LLEN - 1)];
            v.y = x[rb + min(base + 1, LLEN - 1)];
            v.z = x[rb + min(base + 2, LLEN - 1)];
            v.w = x[rb + min(base + 3, LLEN - 1)];
        }
        int a = row * 28 + (row >> 5) * 4 + 4 * q;
        *(float4*)&sm[a] = v;
    }
    __syncthreads();

    const int oc = t;
    const int go = t >> 5;

    // ---- conv1: 26 outputs per thread (24 conv2 outputs + k-1=2 halo) ----
    float acc[26];
#pragma unroll
    for (int l = 0; l < 26; ++l) acc[l] = 0.f;

    for (int i = 0; i < 32; ++i) {
        int base = (go * 32 + i) * 28 + go * 4;
        float wv0 = w1T[(i * 3 + 0) * 256 + oc];
        float wv1 = w1T[(i * 3 + 1) * 256 + oc];
        float wv2 = w1T[(i * 3 + 2) * 256 + oc];
#pragma unroll
        for (int q = 0; q < 7; ++q) {
            float4 v = *(const float4*)&sm[base + 4 * q];
#pragma unroll
            for (int j = 0; j < 4; ++j) {
                int e = 4 * q + j;               // 0..27, compile-time
                float xv = (&v.x)[j];
                if (e < 26) acc[e] += wv0 * xv;
                if (e >= 1 && e <= 26) acc[e - 1] += wv1 * xv;
                if (e >= 2) acc[e - 2] += wv2 * xv;   // e-2 <= 25
            }
        }
    }
    float bias1 = b1[oc];
    // shuffled channel this thread produced, in conv2's skewed LDS layout
    int c1 = (oc & 31) * 8 + (oc >> 5);
    int col1 = (c1 >> 5) * 36 + (c1 & 31);

    __syncthreads();                    // all conv1 reads of xs complete
#pragma unroll
    for (int p = 0; p < 26; ++p) sm[p * 288 + col1] = acc[p] + bias1;
    __syncthreads();                    // t1 tile ready

    // ---- conv2: 24 outputs per thread ----
    float acc2[24];
#pragma unroll
    for (int l = 0; l < 24; ++l) acc2[l] = 0.f;

    for (int i4 = 0; i4 < 8; ++i4) {
        float wv[12];
#pragma unroll
        for (int z = 0; z < 12; ++z) wv[z] = w2T[(i4 * 12 + z) * 256 + oc];
        int colbase = go * 36 + i4 * 4;
#pragma unroll
        for (int p = 0; p < 26; ++p) {
            float4 rv = *(const float4*)&sm[p * 288 + colbase];
#pragma unroll
            for (int cc = 0; cc < 4; ++cc) {
                float xv = (&rv.x)[cc];
#pragma unroll
                for (int k = 0; k < 3; ++k) {
                    int l = p - k;
                    if (l >= 0 && l < 24) acc2[l] += wv[cc * 3 + k] * xv;
                }
            }
            // cap in-flight ds_read batching (VGPR pressure), keep indices static
            if ((p & 3) == 3) __builtin_amdgcn_sched_barrier(0);
        }
    }
    float bias2 = b2[oc];
    int nc = (oc & 31) * 8 + (oc >> 5);
    float* dst = t2 + (size_t)(b * L2V + l0) * CCH + nc;
#pragma unroll
    for (int l = 0; l < 24; ++l) {
        if (l0 + l < L2V) dst[(size_t)l * CCH] = acc2[l] + bias2;
    }
}

// ---------- K3: per-column sort + attention gate, in-place on t2 ----------
__device__ __forceinline__ void ce_pair(float& a, float& b, bool up) {
    float lo = fminf(a, b), hi = fmaxf(a, b);
    a = up ? lo : hi;
    b = up ? hi : lo;
}

// xor-shuffle within 32-lane halves via ds_swizzle immediate (no addr-calc VALU)
template<int LM>
__device__ __forceinline__ float swz(float x) {
    return __int_as_float(__builtin_amdgcn_ds_swizzle(__float_as_int(x), (LM << 10) | 0x1F));
}

// One merge step for ALL 4 columns at once: 16 independent shuffle->minmax chains
// per stage -> DS latency hidden by ILP.
template<int K, int J>
__device__ __forceinline__ void mstep(float v[4][4], int lane) {
    if constexpr (J >= 4) {
        constexpr int LM = J >> 2;
        const bool upper = (lane & LM) != 0;
#pragma unroll
        for (int r = 0; r < 4; ++r) {
            const bool dirUp = (((4 * lane + r) & K) == 0);   // indep of column
            const bool keepMin = (dirUp != upper);
#pragma unroll
            for (int c = 0; c < 4; ++c) {
                float other;
                if constexpr (LM == 32) other = __shfl_xor(v[c][r], 32, 64);
                else other = swz<LM>(v[c][r]);
                float lo = fminf(v[c][r], other), hi = fmaxf(v[c][r], other);
                v[c][r] = keepMin ? lo : hi;
            }
        }
    } else if constexpr (J == 2) {
#pragma unroll
        for (int r = 0; r < 2; ++r) {
            const bool up = (((4 * lane + r) & K) == 0);
#pragma unroll
            for (int c = 0; c < 4; ++c) ce_pair(v[c][r], v[c][r + 2], up);
        }
    } else {
#pragma unroll
        for (int r = 0; r < 4; r += 2) {
            const bool up = (((4 * lane + r) & K) == 0);
#pragma unroll
            for (int c = 0; c < 4; ++c) ce_pair(v[c][r], v[c][r + 1], up);
        }
    }
    if constexpr (J > 1) mstep<K, (J >> 1)>(v, lane);
}

template<int K>
__device__ __forceinline__ void msort(float v[4][4], int lane) {
    mstep<K, (K >> 1)>(v, lane);
    if constexpr (K < 256) msort<(K << 1)>(v, lane);
}

// One wave handles 4 columns. No inter-wave coupling: no __syncthreads.
__global__ __launch_bounds__(256, 5) void attn_kernel(float* __restrict__ t2,
                                                      const float* __restrict__ wt1T,
                                                      const float* __restrict__ wt2T,
                                                      const float* __restrict__ ba1,
                                                      const float* __restrict__ ba2) {
    __shared__ float sm[8192];           // 4 waves * 2048 floats = 32768 B
    const int t = threadIdx.x;
    const int wv = t >> 6;
    const int lane = t & 63;
    const int wbase = wv << 11;
    const int go = lane >> 3;            // group of outputs o = 4*lane+r

    float4 ba1v = *(const float4*)&ba1[4 * lane];
    float4 ba2v = *(const float4*)&ba2[4 * lane];

    const int colBase = blockIdx.x * 16 + wv * 4;   // grid sized exactly: always valid

    float4 hv[4];
#pragma unroll
    for (int cc = 0; cc < 4; ++cc) {
        hv[cc] = *(const float4*)(t2 + (size_t)(colBase + cc) * CCH + 4 * lane);
    }
    // h -> cat chunks 4..7 (xor-swizzled)
#pragma unroll
    for (int r = 0; r < 4; ++r) {
        int e = 4 * lane + r;
        int ch = (e >> 6) + 4;
        int slot = ch * 64 + ((e & 63) ^ ch);
        float4 vvv = make_float4((&hv[0].x)[r], (&hv[1].x)[r], (&hv[2].x)[r], (&hv[3].x)[r]);
        *(float4*)&sm[wbase + slot * 4] = vvv;
    }
    // sort all 4 columns simultaneously (interleaved stages)
    float v[4][4];
#pragma unroll
    for (int cc = 0; cc < 4; ++cc)
#pragma unroll
        for (int r = 0; r < 4; ++r) v[cc][r] = (&hv[cc].x)[r];
    msort<2>(v, lane);

    // sorted -> cat chunks 0..3 (xor-swizzled)
#pragma unroll
    for (int r = 0; r < 4; ++r) {
        int e = 4 * lane + r;
        int ch = e >> 6;
        int slot = ch * 64 + ((e & 63) ^ ch);
        float4 vvv = make_float4(v[0][r], v[1][r], v[2][r], v[3][r]);
        *(float4*)&sm[wbase + slot * 4] = vvv;
    }

    // a1[o] = ba1[o] + sum_i wa1[o][i] * cat[go*64+i]
    float4 acc[4];
#pragma unroll
    for (int cc = 0; cc < 4; ++cc) acc[cc] = make_float4(0.f, 0.f, 0.f, 0.f);
#pragma unroll 4
    for (int i = 0; i < 64; ++i) {
        float4 w4 = *(const float4*)&wt1T[i * 256 + 4 * lane];
        float4 cv = *(const float4*)&sm[wbase + (go * 64 + (i ^ go)) * 4];
#pragma unroll
        for (int cc = 0; cc < 4; ++cc) {
            float cvv = (&cv.x)[cc];
            acc[cc].x += w4.x * cvv;
            acc[cc].y += w4.y * cvv;
            acc[cc].z += w4.z * cvv;
            acc[cc].w += w4.w * cvv;
        }
    }
    // + bias, store a1 into reused buffer (padded: slotA = 5*lane + r, max 318 < 512)
#pragma unroll
    for (int r = 0; r < 4; ++r) {
        float bb = (&ba1v.x)[r];
        float4 vvv = make_float4((&acc[0].x)[r] + bb, (&acc[1].x)[r] + bb,
                                 (&acc[2].x)[r] + bb, (&acc[3].x)[r] + bb);
        *(float4*)&sm[wbase + (5 * lane + r) * 4] = vvv;
    }

    // a2[c] = sigmoid(ba2[c] + sum_i wa2[c][i] * a1[(j%8)*32 + j/8]), j = gc*32+i
    float4 acc2[4];
#pragma unroll
    for (int cc = 0; cc < 4; ++cc) acc2[cc] = make_float4(0.f, 0.f, 0.f, 0.f);
#pragma unroll 4
    for (int i = 0; i < 32; ++i) {
        float4 w4 = *(const float4*)&wt2T[i * 256 + 4 * lane];
        int idx = ((i & 7) << 5) + (go << 2) + (i >> 3);
        int slotA = idx + (idx >> 2);
        float4 av = *(const float4*)&sm[wbase + slotA * 4];
#pragma unroll
        for (int cc = 0; cc < 4; ++cc) {
            float avv = (&av.x)[cc];
            acc2[cc].x += w4.x * avv;
            acc2[cc].y += w4.y * avv;
            acc2[cc].z += w4.z * avv;
            acc2[cc].w += w4.w * avv;
        }
    }
    // gate + in-place store
#pragma unroll
    for (int cc = 0; cc < 4; ++cc) {
        float zx = acc2[cc].x + ba2v.x;
        float zy = acc2[cc].y + ba2v.y;
        float zz = acc2[cc].z + ba2v.z;
        float zw = acc2[cc].w + ba2v.w;
        float4 res;
        res.x = hv[cc].x * (1.f / (1.f + __expf(-zx)));
        res.y = hv[cc].y * (1.f / (1.f + __expf(-zy)));
        res.z = hv[cc].z * (1.f / (1.f + __expf(-zz)));
        res.w = hv[cc].w * (1.f / (1.f + __expf(-zw)));
        *(float4*)(t2 + (size_t)(colBase + cc) * CCH + 4 * lane) = res;
    }
}

// ---------- K4: grouped conv k=5 over t2 [B,L2,C] -> out [B,C,L3] ----------
// LDS [36][256] = 36 KB: compute reads are 2x broadcast (free), staging writes
// 1KB-contiguous per wave -> conflict-equivalent to skewed layout, 4 blocks/CU.
__global__ __launch_bounds__(256, 4) void conv3_kernel(const float* __restrict__ hm,
                                                       const float* __restrict__ w3T,
                                                       const float* __restrict__ b3,
                                                       float* __restrict__ out) {
    __shared__ float ts[9216];  // [36][256]
    const int b = blockIdx.y;
    const int l0 = blockIdx.x * 32;
    const int t = threadIdx.x;

#pragma unroll
    for (int j = 0; j < 9; ++j) {
        int f = t + 256 * j;            // exactly 2304 = 36*64
        int p = f >> 6;
        int c4 = (f & 63) * 4;
        int row = min(l0 + p, L2V - 1);
        float4 v = *(const float4*)(hm + (size_t)(b * L2V + row) * CCH + c4);
        *(float4*)&ts[p * 256 + c4] = v;
    }
    __syncthreads();

    const int oc = t;
    const int go = t >> 5;
    float acc[32];
#pragma unroll
    for (int l = 0; l < 32; ++l) acc[l] = 0.f;

    for (int i4 = 0; i4 < 8; ++i4) {
        float wv[20];
#pragma unroll
        for (int z = 0; z < 20; ++z) wv[z] = w3T[(i4 * 20 + z) * 256 + oc];
        int colbase = go * 32 + i4 * 4;
#pragma unroll
        for (int p = 0; p < 36; ++p) {
            float4 rv = *(const float4*)&ts[p * 256 + colbase];
#pragma unroll
            for (int cc = 0; cc < 4; ++cc) {
                float xv = (&rv.x)[cc];
#pragma unroll
                for (int k = 0; k < 5; ++k) {
                    int l = p - k;
                    if (l >= 0 && l < 32) acc[l] += wv[cc * 5 + k] * xv;
                }
            }
        }
    }
    float bias = b3[oc];
    float* dst = out + (size_t)(b * CCH + oc) * L3V + l0;
#pragma unroll
    for (int l4 = 0; l4 < 8; ++l4) {
        int gl = l0 + 4 * l4;
        if (gl + 3 < L3V) {
            float4 v;
            v.x = acc[4 * l4 + 0] + bias;
            v.y = acc[4 * l4 + 1] + bias;
            v.z = acc[4 * l4 + 2] + bias;
            v.w = acc[4 * l4 + 3] + bias;
            *(float4*)(dst + 4 * l4) = v;
        } else {
#pragma unroll
            for (int c = 0; c < 4; ++c) {
                if (gl + c < L3V) dst[4 * l4 + c] = acc[4 * l4 + c] + bias;
            }
        }
    }
}

extern "C" void kernel_launch(void* const* d_in, const int* in_sizes, int n_in,
                              void* d_out, int out_size, void* d_ws, size_t ws_size,
                              hipStream_t stream) {
    const float* x   = (const float*)d_in[0];
    const float* w1  = (const float*)d_in[1];
    const float* b1  = (const float*)d_in[2];
    const float* w2  = (const float*)d_in[3];
    const float* b2  = (const float*)d_in[4];
    const float* wa1 = (const float*)d_in[5];
    const float* ba1 = (const float*)d_in[6];
    const float* wa2 = (const float*)d_in[7];
    const float* ba2 = (const float*)d_in[8];
    const float* w3  = (const float*)d_in[9];
    const float* b3  = (const float*)d_in[10];
    float* out = (float*)d_out;

    char* ws = (char*)d_ws;
    float* t2   = (float*)(ws + ((size_t)32 << 20));            // 8*4092*256 f32 = 33.5 MB
    float* wt1T = (float*)(ws + ((size_t)64 << 20));            // 64*256 f32
    float* wt2T = wt1T + 64 * 256;                              // 32*256 f32
    float* w1T  = wt2T + 32 * 256;                              // 96*256 f32
    float* w2T  = w1T + 96 * 256;                               // 96*256 f32
    float* w3T  = w2T + 96 * 256;                               // 160*256 f32

    hipLaunchKernelGGL(prep_kernel, dim3(448), dim3(256), 0, stream,
                       wa1, wa2, w1, w2, w3, wt1T, wt2T, w1T, w2T, w3T);
    hipLaunchKernelGGL(conv12_kernel, dim3(171, BB), dim3(256), 0, stream,
                       x, w1T, b1, w2T, b2, t2);
    hipLaunchKernelGGL(attn_kernel, dim3(2046), dim3(256), 0, stream, t2, wt1T, wt2T, ba1, ba2);
    hipLaunchKernelGGL(conv3_kernel, dim3(128, BB), dim3(256), 0, stream, t2, w3T, b3, out);
}